// Round 9
// baseline (860.173 us; speedup 1.0000x reference)
//
#include <hip/hip_runtime.h>

#define N_NODES 50000
#define N_EDGES 800000
#define D_EDGE 64
#define D_NODE 64
#define D_IN 192
#define D_HID 256
#define D_OUT 64

#define BS 128            // nodes per bucket
#define NBK 391           // buckets per side (391*128 = 50048 >= 50000)
#define NC (2*NBK)        // 782 bucket-sides (in-side then out-side)

typedef __attribute__((ext_vector_type(8))) short bf16x8;
typedef __attribute__((ext_vector_type(4))) float f32x4;

__device__ inline ushort f2bf(float f) {
    union { float f; unsigned u; } v; v.f = f;
    unsigned r = v.u + 0x7fff + ((v.u >> 16) & 1);   // round-to-nearest-even
    return (ushort)(r >> 16);
}

// ---------------------------------------------------------------------------
// K1: coarse histogram over NC (side,bucket) counters, LDS-aggregated.
// ---------------------------------------------------------------------------
__global__ __launch_bounds__(256) void chist_kernel(
    const int* __restrict__ senders, const int* __restrict__ receivers,
    int* __restrict__ gcnt) {
    __shared__ int lcnt[NC];
    for (int i = threadIdx.x; i < NC; i += 256) lcnt[i] = 0;
    __syncthreads();
    const int stride = gridDim.x * 256;
    const int nvec = N_EDGES / 4;   // 200000
    const int4* rv = (const int4*)receivers;
    const int4* sv = (const int4*)senders;
    for (int i = blockIdx.x * 256 + threadIdx.x; i < nvec; i += stride) {
        int4 r = rv[i], s = sv[i];
        atomicAdd(&lcnt[r.x / BS], 1);
        atomicAdd(&lcnt[r.y / BS], 1);
        atomicAdd(&lcnt[r.z / BS], 1);
        atomicAdd(&lcnt[r.w / BS], 1);
        atomicAdd(&lcnt[NBK + s.x / BS], 1);
        atomicAdd(&lcnt[NBK + s.y / BS], 1);
        atomicAdd(&lcnt[NBK + s.z / BS], 1);
        atomicAdd(&lcnt[NBK + s.w / BS], 1);
    }
    __syncthreads();
    for (int i = threadIdx.x; i < NC; i += 256) {
        int c = lcnt[i];
        if (c) atomicAdd(&gcnt[i], c);
    }
}

// ---------------------------------------------------------------------------
// K2: exclusive scan of the NC bucket counts -> coffs[NC+1] + cursor copy.
// ---------------------------------------------------------------------------
__global__ __launch_bounds__(1024) void cscan_kernel(
    const int* __restrict__ gcnt, int* __restrict__ coffs, int* __restrict__ gcur) {
    __shared__ int s[1024];
    const int t = threadIdx.x;
    int v = (t < NC) ? gcnt[t] : 0;
    s[t] = v;
    __syncthreads();
    for (int off = 1; off < 1024; off <<= 1) {
        int u = (t >= off) ? s[t - off] : 0;
        __syncthreads();
        s[t] += u;
        __syncthreads();
    }
    int excl = s[t] - v;
    if (t < NC) { coffs[t] = excl; gcur[t] = excl; }
    if (t == NC - 1) coffs[NC] = excl + v;   // == 2*N_EDGES
}

// ---------------------------------------------------------------------------
// K3: part — the data-moving partition. Block = 256 thr, 2048 edges.
// Phase A: LDS-rank each edge's two (side,bucket) targets.
// Phase B: reserve frontier space in gcur.
// Phase C: store dests in LDS; write node ids (scattered 4B).
// Phase D: wave-cooperative copy: read edge rows SEQUENTIALLY (1 KB/instr),
//          convert to bf16, write 128 B records to both dests.
// ---------------------------------------------------------------------------
#define P_EPT 8
#define P_BLK (256 * P_EPT)   // 2048 edges per block
__global__ __launch_bounds__(256) void part_kernel(
    const int* __restrict__ senders, const int* __restrict__ receivers,
    const float* __restrict__ ef,
    int* __restrict__ gcur,
    ushort* __restrict__ data_buf,   // [2*N_EDGES][64] bf16 records
    int* __restrict__ node_buf) {    // [2*N_EDGES] node ids
    __shared__ int lcnt[NC];
    __shared__ int lbase[NC];
    __shared__ int dsti[P_BLK];
    __shared__ int dsto[P_BLK];
    const int tid = threadIdx.x;
    for (int i = tid; i < NC; i += 256) lcnt[i] = 0;
    __syncthreads();
    const int base_e = blockIdx.x * P_BLK;
    int rr[P_EPT], ss[P_EPT], rkr[P_EPT], rks[P_EPT];
#pragma unroll
    for (int j = 0; j < P_EPT; j++) {
        int e = base_e + j * 256 + tid;
        if (e < N_EDGES) {
            int r = receivers[e], sd = senders[e];
            rr[j] = r; ss[j] = sd;
            rkr[j] = atomicAdd(&lcnt[r / BS], 1);
            rks[j] = atomicAdd(&lcnt[NBK + sd / BS], 1);
        } else {
            rr[j] = -1;
        }
    }
    __syncthreads();
    for (int i = tid; i < NC; i += 256) {
        int c = lcnt[i];
        lbase[i] = c ? atomicAdd(&gcur[i], c) : 0;
    }
    __syncthreads();
#pragma unroll
    for (int j = 0; j < P_EPT; j++) {
        int k = j * 256 + tid;
        if (rr[j] >= 0) {
            int di = lbase[rr[j] / BS] + rkr[j];
            int dq = lbase[NBK + ss[j] / BS] + rks[j];
            dsti[k] = di; dsto[k] = dq;
            node_buf[di] = rr[j];
            node_buf[dq] = ss[j];
        } else {
            dsti[k] = -1; dsto[k] = -1;
        }
    }
    __syncthreads();
    // Phase D: cooperative copy. wave w owns edges [w*512, w*512+512).
    const int w = tid >> 6, lane = tid & 63;
    const int sub4 = lane >> 4;          // edge within quad
    const int l16 = lane & 15;           // 16 lanes cover a 64-col row
    for (int it = 0; it < 128; it++) {
        int k = w * 512 + it * 4 + sub4;
        int di = dsti[k], dq = dsto[k];
        if (di < 0) continue;
        int e = base_e + k;
        f32x4 v = *(const f32x4*)(ef + (size_t)e * D_EDGE + l16 * 4);
        ushort4 o;
        o.x = f2bf(v[0]); o.y = f2bf(v[1]); o.z = f2bf(v[2]); o.w = f2bf(v[3]);
        *(ushort4*)(data_buf + (size_t)di * D_EDGE + l16 * 4) = o;
        *(ushort4*)(data_buf + (size_t)dq * D_EDGE + l16 * 4) = o;
    }
}

// ---------------------------------------------------------------------------
// K4: bagg — one 512-thr block per bucket-side. Sequential span scan,
// bank-swizzled 32 KB LDS f32 accumulator, single dump to x.
// Wave-iter: 8 records (sub = lane>>3), lane loads 16 B (8 bf16),
// 8 ds-atomic adds each (swizzle -> 2-way conflict = free).
// ---------------------------------------------------------------------------
__global__ __launch_bounds__(512) void bagg_kernel(
    const ushort* __restrict__ data_buf, const int* __restrict__ node_buf,
    const int* __restrict__ coffs, ushort* __restrict__ x) {
    __shared__ float acc[BS * 64];   // 32 KB
    const int i = blockIdx.x;
    const int side = (i >= NBK) ? 1 : 0;
    const int node_base = (side ? i - NBK : i) * BS;
    const int tid = threadIdx.x;
    for (int t = tid; t < BS * 64; t += 512) acc[t] = 0.f;
    __syncthreads();

    const int p0 = coffs[i], p1 = coffs[i + 1];
    const int lane = tid & 63, wv = tid >> 6;   // 8 waves
    const int sub = lane >> 3;                  // record in octet
    const int c8 = (lane & 7) * 8;              // col base
    for (int rb = p0 + wv * 8; rb < p1; rb += 64) {
        int rec = rb + sub;
        if (rec < p1) {
            uint4 d = *(const uint4*)(data_buf + (size_t)rec * D_EDGE + c8);
            int row = node_buf[rec] - node_base;
            int sw = (row & 7) << 3;
            float* a = acc + row * 64;
            atomicAdd(a + ((c8 + 0) ^ sw), __uint_as_float(d.x << 16));
            atomicAdd(a + ((c8 + 1) ^ sw), __uint_as_float(d.x & 0xffff0000u));
            atomicAdd(a + ((c8 + 2) ^ sw), __uint_as_float(d.y << 16));
            atomicAdd(a + ((c8 + 3) ^ sw), __uint_as_float(d.y & 0xffff0000u));
            atomicAdd(a + ((c8 + 4) ^ sw), __uint_as_float(d.z << 16));
            atomicAdd(a + ((c8 + 5) ^ sw), __uint_as_float(d.z & 0xffff0000u));
            atomicAdd(a + ((c8 + 6) ^ sw), __uint_as_float(d.w << 16));
            atomicAdd(a + ((c8 + 7) ^ sw), __uint_as_float(d.w & 0xffff0000u));
        }
    }
    __syncthreads();

    for (int t = tid; t < BS * 64; t += 512) {
        int row = t >> 6, col = t & 63;
        int node = node_base + row;
        if (node < N_NODES) {
            float v = acc[row * 64 + (col ^ ((row & 7) << 3))];
            x[(size_t)node * 128 + side * 64 + col] = f2bf(v);
        }
    }
}

// ---------------------------------------------------------------------------
// K5: pack W1/W2 (f32) into bf16 fragment-major layout for MFMA B-operands.
// ---------------------------------------------------------------------------
__global__ __launch_bounds__(256) void pack_w_kernel(
    const float* __restrict__ W1, const float* __restrict__ W2,
    ushort* __restrict__ w1p, ushort* __restrict__ w2p) {
    int idx = blockIdx.x * 256 + threadIdx.x;   // 8192 total
    if (idx < 6144) {
        int nt = idx / 384, rem = idx % 384;
        int s = rem / 64, l = rem % 64;
        int g = l >> 4, c = l & 15;
        ushort* dst = w1p + (size_t)idx * 8;
#pragma unroll
        for (int j = 0; j < 8; j++) {
            int k = s * 32 + g * 8 + j;
            dst[j] = f2bf(W1[(size_t)k * D_HID + nt * 16 + c]);
        }
    } else if (idx < 8192) {
        int id2 = idx - 6144;
        int nt = id2 / 512, rem = id2 % 512;
        int s = rem / 64, l = rem % 64;
        int g = l >> 4, c = l & 15;
        ushort* dst = w2p + (size_t)id2 * 8;
#pragma unroll
        for (int j = 0; j < 8; j++) {
            int k = s * 32 + g * 8 + j;
            dst[j] = f2bf(W2[(size_t)k * D_OUT + nt * 16 + c]);
        }
    }
}

// ---------------------------------------------------------------------------
// K6: MFMA MLP. Block = 256 thr (4 waves), 32 nodes (2 mtiles).
// ---------------------------------------------------------------------------
__global__ __launch_bounds__(256) void mlp_mfma_kernel(
    const ushort* __restrict__ x,        // [N][128] bf16
    const float* __restrict__ node_feat, // [N][64]
    const ushort* __restrict__ w1p, const float* __restrict__ b1,
    const ushort* __restrict__ w2p, const float* __restrict__ b2,
    float* __restrict__ out) {
    __shared__ ushort h_lds[32][D_HID + 8];
    const int tid = threadIdx.x;
    const int wave = tid >> 6, lane = tid & 63;
    const int g = lane >> 4, c = lane & 15;
    const int node0 = blockIdx.x * 32;

    f32x4 acc[2][4];
#pragma unroll
    for (int m = 0; m < 2; m++)
#pragma unroll
        for (int q = 0; q < 4; q++) acc[m][q] = (f32x4){0.f, 0.f, 0.f, 0.f};

    const bf16x8* w1v = (const bf16x8*)w1p;
    const bf16x8* w2v = (const bf16x8*)w2p;

    int row0 = node0 + c;      if (row0 > N_NODES - 1) row0 = N_NODES - 1;
    int row1 = node0 + 16 + c; if (row1 > N_NODES - 1) row1 = N_NODES - 1;

#pragma unroll
    for (int s = 0; s < 6; s++) {
        bf16x8 a0, a1;
        if (s < 4) {
            a0 = *(const bf16x8*)(x + (size_t)row0 * 128 + s * 32 + g * 8);
            a1 = *(const bf16x8*)(x + (size_t)row1 * 128 + s * 32 + g * 8);
        } else {
            const float* p0 = node_feat + (size_t)row0 * D_NODE + (s - 4) * 32 + g * 8;
            const float* p1 = node_feat + (size_t)row1 * D_NODE + (s - 4) * 32 + g * 8;
            union { bf16x8 v; ushort u[8]; } t0, t1;
#pragma unroll
            for (int j = 0; j < 8; j++) { t0.u[j] = f2bf(p0[j]); t1.u[j] = f2bf(p1[j]); }
            a0 = t0.v; a1 = t1.v;
        }
#pragma unroll
        for (int q = 0; q < 4; q++) {
            int nt = wave + q * 4;
            bf16x8 b = w1v[(nt * 6 + s) * 64 + lane];
            acc[0][q] = __builtin_amdgcn_mfma_f32_16x16x32_bf16(a0, b, acc[0][q], 0, 0, 0);
            acc[1][q] = __builtin_amdgcn_mfma_f32_16x16x32_bf16(a1, b, acc[1][q], 0, 0, 0);
        }
    }

#pragma unroll
    for (int q = 0; q < 4; q++) {
        int nt = wave + q * 4;
        float bv = b1[nt * 16 + c];
#pragma unroll
        for (int mt = 0; mt < 2; mt++)
#pragma unroll
            for (int r = 0; r < 4; r++) {
                int row = mt * 16 + g * 4 + r;
                h_lds[row][nt * 16 + c] = f2bf(fmaxf(acc[mt][q][r] + bv, 0.f));
            }
    }
    __syncthreads();

    f32x4 acc2[2];
    acc2[0] = (f32x4){0.f, 0.f, 0.f, 0.f};
    acc2[1] = (f32x4){0.f, 0.f, 0.f, 0.f};
#pragma unroll
    for (int s = 0; s < 8; s++) {
        bf16x8 b = w2v[(wave * 8 + s) * 64 + lane];
#pragma unroll
        for (int mt = 0; mt < 2; mt++) {
            bf16x8 a = *(const bf16x8*)(&h_lds[mt * 16 + c][s * 32 + g * 8]);
            acc2[mt] = __builtin_amdgcn_mfma_f32_16x16x32_bf16(a, b, acc2[mt], 0, 0, 0);
        }
    }
    float b2v = b2[wave * 16 + c];
#pragma unroll
    for (int mt = 0; mt < 2; mt++)
#pragma unroll
        for (int r = 0; r < 4; r++) {
            int row = node0 + mt * 16 + g * 4 + r;
            if (row < N_NODES) out[(size_t)row * D_OUT + wave * 16 + c] = acc2[mt][r] + b2v;
        }
}

extern "C" void kernel_launch(void* const* d_in, const int* in_sizes, int n_in,
                              void* d_out, int out_size, void* d_ws, size_t ws_size,
                              hipStream_t stream) {
    const float* node_feat = (const float*)d_in[0];
    const float* edge_feat = (const float*)d_in[1];
    const int* senders     = (const int*)d_in[2];
    const int* receivers   = (const int*)d_in[3];
    const float* W1        = (const float*)d_in[4];
    const float* b1        = (const float*)d_in[5];
    const float* W2        = (const float*)d_in[6];
    const float* b2        = (const float*)d_in[7];
    float* out = (float*)d_out;

    // workspace layout
    ushort* x        = (ushort*)d_ws;                        // 12.8 MB
    ushort* data_buf = x + (size_t)N_NODES * 128;            // 2*N_EDGES*64 bf16 = 204.8 MB
    ushort* w1p      = data_buf + (size_t)2 * N_EDGES * D_EDGE;
    ushort* w2p      = w1p + 16 * 6 * 64 * 8;
    int* node_buf    = (int*)(w2p + 4 * 8 * 64 * 8);         // 2*N_EDGES ints = 6.4 MB
    int* gcnt        = node_buf + (size_t)2 * N_EDGES;       // NC
    int* coffs       = gcnt + NC;                            // NC+1
    int* gcur        = coffs + (NC + 1);                     // NC

    hipMemsetAsync(gcnt, 0, NC * sizeof(int), stream);

    chist_kernel<<<dim3(256), dim3(256), 0, stream>>>(senders, receivers, gcnt);
    cscan_kernel<<<dim3(1), dim3(1024), 0, stream>>>(gcnt, coffs, gcur);
    {
        dim3 grid((N_EDGES + P_BLK - 1) / P_BLK);   // 391
        part_kernel<<<grid, dim3(256), 0, stream>>>(senders, receivers, edge_feat,
                                                    gcur, data_buf, node_buf);
    }
    pack_w_kernel<<<dim3(32), dim3(256), 0, stream>>>(W1, W2, w1p, w2p);
    bagg_kernel<<<dim3(NC), dim3(512), 0, stream>>>(data_buf, node_buf, coffs, x);
    {
        dim3 grid((N_NODES + 31) / 32), block(256);
        mlp_mfma_kernel<<<grid, block, 0, stream>>>(x, node_feat, w1p, b1, w2p, b2, out);
    }
}

// Round 10
// 149.568 us; speedup vs baseline: 5.7510x; 5.7510x over previous
//
#include <hip/hip_runtime.h>

#define N_NODES 50000
#define N_EDGES 800000
#define D_EDGE 64
#define D_NODE 64
#define D_IN 192
#define D_HID 256
#define D_OUT 64

#define BS 128            // nodes per bucket (power of 2: local id fits 7 bits)
#define NBK 391           // buckets per side (391*128 = 50048 >= 50000)
#define NC (2*NBK)        // 782 bucket-sides (in-side then out-side)

typedef __attribute__((ext_vector_type(8))) short bf16x8;
typedef __attribute__((ext_vector_type(4))) float f32x4;

__device__ inline ushort f2bf(float f) {
    union { float f; unsigned u; } v; v.f = f;
    unsigned r = v.u + 0x7fff + ((v.u >> 16) & 1);   // round-to-nearest-even
    return (ushort)(r >> 16);
}

// ---------------------------------------------------------------------------
// K1: coarse histogram over NC (side,bucket) counters, LDS-aggregated.
// ---------------------------------------------------------------------------
__global__ __launch_bounds__(256) void chist_kernel(
    const int* __restrict__ senders, const int* __restrict__ receivers,
    int* __restrict__ gcnt) {
    __shared__ int lcnt[NC];
    for (int i = threadIdx.x; i < NC; i += 256) lcnt[i] = 0;
    __syncthreads();
    const int stride = gridDim.x * 256;
    const int nvec = N_EDGES / 4;   // 200000
    const int4* rv = (const int4*)receivers;
    const int4* sv = (const int4*)senders;
    for (int i = blockIdx.x * 256 + threadIdx.x; i < nvec; i += stride) {
        int4 r = rv[i], s = sv[i];
        atomicAdd(&lcnt[r.x / BS], 1);
        atomicAdd(&lcnt[r.y / BS], 1);
        atomicAdd(&lcnt[r.z / BS], 1);
        atomicAdd(&lcnt[r.w / BS], 1);
        atomicAdd(&lcnt[NBK + s.x / BS], 1);
        atomicAdd(&lcnt[NBK + s.y / BS], 1);
        atomicAdd(&lcnt[NBK + s.z / BS], 1);
        atomicAdd(&lcnt[NBK + s.w / BS], 1);
    }
    __syncthreads();
    for (int i = threadIdx.x; i < NC; i += 256) {
        int c = lcnt[i];
        if (c) atomicAdd(&gcnt[i], c);
    }
}

// ---------------------------------------------------------------------------
// K2: exclusive scan of the NC bucket counts -> coffs[NC+1] + cursor copy.
// ---------------------------------------------------------------------------
__global__ __launch_bounds__(1024) void cscan_kernel(
    const int* __restrict__ gcnt, int* __restrict__ coffs, int* __restrict__ gcur) {
    __shared__ int s[1024];
    const int t = threadIdx.x;
    int v = (t < NC) ? gcnt[t] : 0;
    s[t] = v;
    __syncthreads();
    for (int off = 1; off < 1024; off <<= 1) {
        int u = (t >= off) ? s[t - off] : 0;
        __syncthreads();
        s[t] += u;
        __syncthreads();
    }
    int excl = s[t] - v;
    if (t < NC) { coffs[t] = excl; gcur[t] = excl; }
    if (t == NC - 1) coffs[NC] = excl + v;   // == 2*N_EDGES
}

// ---------------------------------------------------------------------------
// K3: bin — write packed (local_node<<20 | edge) ints into per-bucket
// regions. Two-phase LDS ranking -> dense frontier writes (4 B each).
// ---------------------------------------------------------------------------
#define F1_EPT 16
#define F1_BLK_EDGES (256 * F1_EPT)   // 4096
__global__ __launch_bounds__(256) void bin_kernel(
    const int* __restrict__ senders, const int* __restrict__ receivers,
    int* __restrict__ gcur, int* __restrict__ pair_buf) {
    __shared__ int lcnt[NC];
    __shared__ int lbase[NC];
    for (int i = threadIdx.x; i < NC; i += 256) lcnt[i] = 0;
    __syncthreads();
    const int base_e = blockIdx.x * F1_BLK_EDGES;
    int rr[F1_EPT], ss[F1_EPT], rkr[F1_EPT], rks[F1_EPT];
#pragma unroll
    for (int j = 0; j < F1_EPT; j++) {
        int e = base_e + j * 256 + threadIdx.x;
        if (e < N_EDGES) {
            int r = receivers[e], sd = senders[e];
            rr[j] = r; ss[j] = sd;
            rkr[j] = atomicAdd(&lcnt[r / BS], 1);
            rks[j] = atomicAdd(&lcnt[NBK + sd / BS], 1);
        } else {
            rr[j] = -1;
        }
    }
    __syncthreads();
    for (int i = threadIdx.x; i < NC; i += 256) {
        int c = lcnt[i];
        lbase[i] = c ? atomicAdd(&gcur[i], c) : 0;
    }
    __syncthreads();
#pragma unroll
    for (int j = 0; j < F1_EPT; j++) {
        if (rr[j] >= 0) {
            int e = base_e + j * 256 + threadIdx.x;
            pair_buf[lbase[rr[j] / BS] + rkr[j]] = ((rr[j] & (BS - 1)) << 20) | e;
            pair_buf[lbase[NBK + ss[j] / BS] + rks[j]] = ((ss[j] & (BS - 1)) << 20) | e;
        }
    }
}

// ---------------------------------------------------------------------------
// K4: reorder — one block per bucket-side. Sort the bucket's packed entries
// by node into a fine CSR edge-id array (dense-span writes only).
// ---------------------------------------------------------------------------
__global__ __launch_bounds__(256) void reorder_kernel(
    const int* __restrict__ pair_buf, const int* __restrict__ coffs,
    int* __restrict__ eidx, int* __restrict__ offs_in, int* __restrict__ offs_out) {
    __shared__ int cur[BS];
    __shared__ int ss[256];
    const int i = blockIdx.x;
    const int side = (i >= NBK) ? 1 : 0;
    const int node_base = (side ? i - NBK : i) * BS;
    const int t = threadIdx.x;
    if (t < BS) cur[t] = 0;
    __syncthreads();
    const int p0 = coffs[i], p1 = coffs[i + 1];
    for (int p = p0 + t; p < p1; p += 256)
        atomicAdd(&cur[pair_buf[p] >> 20], 1);
    __syncthreads();
    int v = (t < BS) ? cur[t] : 0;
    ss[t] = v;
    __syncthreads();
    for (int off = 1; off < 256; off <<= 1) {
        int u = (t >= off) ? ss[t - off] : 0;
        __syncthreads();
        ss[t] += u;
        __syncthreads();
    }
    int ex = ss[t] - v;   // exclusive prefix within bucket
    int* offs = side ? offs_out : offs_in;
    if (t < BS) {
        cur[t] = ex;
        int node = node_base + t;
        if (node < N_NODES) offs[node] = p0 + ex;
    }
    if (t == 0 && node_base + BS >= N_NODES) offs[N_NODES] = p1;  // sentinel (last bucket)
    __syncthreads();
    for (int p = p0 + t; p < p1; p += 256) {
        int q = pair_buf[p];
        int rk = atomicAdd(&cur[q >> 20], 1);
        eidx[p0 + rk] = q & 0xFFFFF;
    }
}

// ---------------------------------------------------------------------------
// K5: gather — one wave per (node, side). Lane loads float4 (16 B): the
// wave covers 4 rows per load instruction (16 lanes/row), 4-way unrolled
// -> 16 rows (4 KB) in flight per wave. shfl_xor reduce across row-groups.
// ---------------------------------------------------------------------------
__global__ __launch_bounds__(256) void gather_kernel(
    const float* __restrict__ edge_feat,
    const int* __restrict__ offs_in, const int* __restrict__ offs_out,
    const int* __restrict__ eidx,
    ushort* __restrict__ x) {          // [N_NODES][128] bf16
    int task = blockIdx.x * 4 + (threadIdx.x >> 6);
    if (task >= 2 * N_NODES) return;
    const int lane = threadIdx.x & 63;
    const int sub = lane >> 4;          // row-group 0..3
    const int c4 = (lane & 15) * 4;     // column base (16 lanes span a 64-col row)
    const int node = task >> 1;
    const int side = task & 1;
    const int* offs = side ? offs_out : offs_in;
    const int b = offs[node], e = offs[node + 1];
    f32x4 acc = {0.f, 0.f, 0.f, 0.f};
    int i = b + sub;
    for (; i + 12 < e; i += 16) {       // 4 rows per group in flight
        int r0 = eidx[i], r1 = eidx[i + 4], r2 = eidx[i + 8], r3 = eidx[i + 12];
        f32x4 v0 = *(const f32x4*)(edge_feat + (size_t)r0 * D_EDGE + c4);
        f32x4 v1 = *(const f32x4*)(edge_feat + (size_t)r1 * D_EDGE + c4);
        f32x4 v2 = *(const f32x4*)(edge_feat + (size_t)r2 * D_EDGE + c4);
        f32x4 v3 = *(const f32x4*)(edge_feat + (size_t)r3 * D_EDGE + c4);
        acc += v0 + v1 + v2 + v3;
    }
    for (; i < e; i += 4) {
        int r = eidx[i];
        acc += *(const f32x4*)(edge_feat + (size_t)r * D_EDGE + c4);
    }
    // reduce across the 4 row-groups (lanes ^16, ^32)
#pragma unroll
    for (int j = 0; j < 4; j++) {
        acc[j] += __shfl_xor(acc[j], 16, 64);
        acc[j] += __shfl_xor(acc[j], 32, 64);
    }
    if (sub == 0) {
        ushort4 o;
        o.x = f2bf(acc[0]); o.y = f2bf(acc[1]);
        o.z = f2bf(acc[2]); o.w = f2bf(acc[3]);
        *(ushort4*)(x + (size_t)node * 128 + side * 64 + c4) = o;
    }
}

// ---------------------------------------------------------------------------
// K6: pack W1/W2 (f32) into bf16 fragment-major layout for MFMA B-operands.
// ---------------------------------------------------------------------------
__global__ __launch_bounds__(256) void pack_w_kernel(
    const float* __restrict__ W1, const float* __restrict__ W2,
    ushort* __restrict__ w1p, ushort* __restrict__ w2p) {
    int idx = blockIdx.x * 256 + threadIdx.x;   // 8192 total
    if (idx < 6144) {
        int nt = idx / 384, rem = idx % 384;
        int s = rem / 64, l = rem % 64;
        int g = l >> 4, c = l & 15;
        ushort* dst = w1p + (size_t)idx * 8;
#pragma unroll
        for (int j = 0; j < 8; j++) {
            int k = s * 32 + g * 8 + j;
            dst[j] = f2bf(W1[(size_t)k * D_HID + nt * 16 + c]);
        }
    } else if (idx < 8192) {
        int id2 = idx - 6144;
        int nt = id2 / 512, rem = id2 % 512;
        int s = rem / 64, l = rem % 64;
        int g = l >> 4, c = l & 15;
        ushort* dst = w2p + (size_t)id2 * 8;
#pragma unroll
        for (int j = 0; j < 8; j++) {
            int k = s * 32 + g * 8 + j;
            dst[j] = f2bf(W2[(size_t)k * D_OUT + nt * 16 + c]);
        }
    }
}

// ---------------------------------------------------------------------------
// K7: MFMA MLP. Block = 256 thr (4 waves), 32 nodes (2 mtiles).
// ---------------------------------------------------------------------------
__global__ __launch_bounds__(256) void mlp_mfma_kernel(
    const ushort* __restrict__ x,        // [N][128] bf16
    const float* __restrict__ node_feat, // [N][64]
    const ushort* __restrict__ w1p, const float* __restrict__ b1,
    const ushort* __restrict__ w2p, const float* __restrict__ b2,
    float* __restrict__ out) {
    __shared__ ushort h_lds[32][D_HID + 8];
    const int tid = threadIdx.x;
    const int wave = tid >> 6, lane = tid & 63;
    const int g = lane >> 4, c = lane & 15;
    const int node0 = blockIdx.x * 32;

    f32x4 acc[2][4];
#pragma unroll
    for (int m = 0; m < 2; m++)
#pragma unroll
        for (int q = 0; q < 4; q++) acc[m][q] = (f32x4){0.f, 0.f, 0.f, 0.f};

    const bf16x8* w1v = (const bf16x8*)w1p;
    const bf16x8* w2v = (const bf16x8*)w2p;

    int row0 = node0 + c;      if (row0 > N_NODES - 1) row0 = N_NODES - 1;
    int row1 = node0 + 16 + c; if (row1 > N_NODES - 1) row1 = N_NODES - 1;

#pragma unroll
    for (int s = 0; s < 6; s++) {
        bf16x8 a0, a1;
        if (s < 4) {
            a0 = *(const bf16x8*)(x + (size_t)row0 * 128 + s * 32 + g * 8);
            a1 = *(const bf16x8*)(x + (size_t)row1 * 128 + s * 32 + g * 8);
        } else {
            const float* p0 = node_feat + (size_t)row0 * D_NODE + (s - 4) * 32 + g * 8;
            const float* p1 = node_feat + (size_t)row1 * D_NODE + (s - 4) * 32 + g * 8;
            union { bf16x8 v; ushort u[8]; } t0, t1;
#pragma unroll
            for (int j = 0; j < 8; j++) { t0.u[j] = f2bf(p0[j]); t1.u[j] = f2bf(p1[j]); }
            a0 = t0.v; a1 = t1.v;
        }
#pragma unroll
        for (int q = 0; q < 4; q++) {
            int nt = wave + q * 4;
            bf16x8 b = w1v[(nt * 6 + s) * 64 + lane];
            acc[0][q] = __builtin_amdgcn_mfma_f32_16x16x32_bf16(a0, b, acc[0][q], 0, 0, 0);
            acc[1][q] = __builtin_amdgcn_mfma_f32_16x16x32_bf16(a1, b, acc[1][q], 0, 0, 0);
        }
    }

#pragma unroll
    for (int q = 0; q < 4; q++) {
        int nt = wave + q * 4;
        float bv = b1[nt * 16 + c];
#pragma unroll
        for (int mt = 0; mt < 2; mt++)
#pragma unroll
            for (int r = 0; r < 4; r++) {
                int row = mt * 16 + g * 4 + r;
                h_lds[row][nt * 16 + c] = f2bf(fmaxf(acc[mt][q][r] + bv, 0.f));
            }
    }
    __syncthreads();

    f32x4 acc2[2];
    acc2[0] = (f32x4){0.f, 0.f, 0.f, 0.f};
    acc2[1] = (f32x4){0.f, 0.f, 0.f, 0.f};
#pragma unroll
    for (int s = 0; s < 8; s++) {
        bf16x8 b = w2v[(wave * 8 + s) * 64 + lane];
#pragma unroll
        for (int mt = 0; mt < 2; mt++) {
            bf16x8 a = *(const bf16x8*)(&h_lds[mt * 16 + c][s * 32 + g * 8]);
            acc2[mt] = __builtin_amdgcn_mfma_f32_16x16x32_bf16(a, b, acc2[mt], 0, 0, 0);
        }
    }
    float b2v = b2[wave * 16 + c];
#pragma unroll
    for (int mt = 0; mt < 2; mt++)
#pragma unroll
        for (int r = 0; r < 4; r++) {
            int row = node0 + mt * 16 + g * 4 + r;
            if (row < N_NODES) out[(size_t)row * D_OUT + wave * 16 + c] = acc2[mt][r] + b2v;
        }
}

extern "C" void kernel_launch(void* const* d_in, const int* in_sizes, int n_in,
                              void* d_out, int out_size, void* d_ws, size_t ws_size,
                              hipStream_t stream) {
    const float* node_feat = (const float*)d_in[0];
    const float* edge_feat = (const float*)d_in[1];
    const int* senders     = (const int*)d_in[2];
    const int* receivers   = (const int*)d_in[3];
    const float* W1        = (const float*)d_in[4];
    const float* b1        = (const float*)d_in[5];
    const float* W2        = (const float*)d_in[6];
    const float* b2        = (const float*)d_in[7];
    float* out = (float*)d_out;

    // workspace layout
    ushort* x   = (ushort*)d_ws;                         // 50000*128 bf16 = 12.8 MB
    ushort* w1p = x + (size_t)N_NODES * 128;             // 49152 bf16
    ushort* w2p = w1p + 16 * 6 * 64 * 8;                 // 16384 bf16
    int* pair_buf = (int*)(w2p + 4 * 8 * 64 * 8);        // 1.6M ints = 6.4 MB
    int* eidx     = pair_buf + (size_t)2 * N_EDGES;      // 1.6M ints = 6.4 MB
    int* offs_in  = eidx + 2 * N_EDGES;                  // N+1
    int* offs_out = offs_in + (N_NODES + 1);             // N+1
    int* gcnt     = offs_out + (N_NODES + 1);            // NC
    int* coffs    = gcnt + NC;                           // NC+1
    int* gcur     = coffs + (NC + 1);                    // NC

    hipMemsetAsync(gcnt, 0, NC * sizeof(int), stream);

    chist_kernel<<<dim3(256), dim3(256), 0, stream>>>(senders, receivers, gcnt);
    cscan_kernel<<<dim3(1), dim3(1024), 0, stream>>>(gcnt, coffs, gcur);
    {
        dim3 grid((N_EDGES + F1_BLK_EDGES - 1) / F1_BLK_EDGES);   // 196
        bin_kernel<<<grid, dim3(256), 0, stream>>>(senders, receivers, gcur, pair_buf);
    }
    reorder_kernel<<<dim3(NC), dim3(256), 0, stream>>>(pair_buf, coffs, eidx,
                                                       offs_in, offs_out);
    pack_w_kernel<<<dim3(32), dim3(256), 0, stream>>>(W1, W2, w1p, w2p);
    {
        const int tasks = 2 * N_NODES;
        dim3 grid((tasks + 3) / 4);
        gather_kernel<<<grid, dim3(256), 0, stream>>>(edge_feat, offs_in, offs_out,
                                                      eidx, x);
    }
    {
        dim3 grid((N_NODES + 31) / 32), block(256);
        mlp_mfma_kernel<<<grid, block, 0, stream>>>(x, node_feat, w1p, b1, w2p, b2, out);
    }
}

// Round 11
// 147.327 us; speedup vs baseline: 5.8385x; 1.0152x over previous
//
#include <hip/hip_runtime.h>

#define N_NODES 50000
#define N_EDGES 800000
#define D_EDGE 64
#define D_NODE 64
#define D_IN 192
#define D_HID 256
#define D_OUT 64

#define BS 128            // nodes per bucket (power of 2: local id fits 7 bits)
#define NBK 391           // buckets per side (391*128 = 50048 >= 50000)
#define NC (2*NBK)        // 782 bucket-sides (in-side then out-side)

typedef __attribute__((ext_vector_type(8))) short bf16x8;
typedef __attribute__((ext_vector_type(4))) float f32x4;

__device__ inline ushort f2bf(float f) {
    union { float f; unsigned u; } v; v.f = f;
    unsigned r = v.u + 0x7fff + ((v.u >> 16) & 1);   // round-to-nearest-even
    return (ushort)(r >> 16);
}

// ---------------------------------------------------------------------------
// K1: coarse histogram over NC (side,bucket) counters, LDS-aggregated.
// ---------------------------------------------------------------------------
__global__ __launch_bounds__(256) void chist_kernel(
    const int* __restrict__ senders, const int* __restrict__ receivers,
    int* __restrict__ gcnt) {
    __shared__ int lcnt[NC];
    for (int i = threadIdx.x; i < NC; i += 256) lcnt[i] = 0;
    __syncthreads();
    const int stride = gridDim.x * 256;
    const int nvec = N_EDGES / 4;   // 200000
    const int4* rv = (const int4*)receivers;
    const int4* sv = (const int4*)senders;
    for (int i = blockIdx.x * 256 + threadIdx.x; i < nvec; i += stride) {
        int4 r = rv[i], s = sv[i];
        atomicAdd(&lcnt[r.x / BS], 1);
        atomicAdd(&lcnt[r.y / BS], 1);
        atomicAdd(&lcnt[r.z / BS], 1);
        atomicAdd(&lcnt[r.w / BS], 1);
        atomicAdd(&lcnt[NBK + s.x / BS], 1);
        atomicAdd(&lcnt[NBK + s.y / BS], 1);
        atomicAdd(&lcnt[NBK + s.z / BS], 1);
        atomicAdd(&lcnt[NBK + s.w / BS], 1);
    }
    __syncthreads();
    for (int i = threadIdx.x; i < NC; i += 256) {
        int c = lcnt[i];
        if (c) atomicAdd(&gcnt[i], c);
    }
}

// ---------------------------------------------------------------------------
// K2: exclusive scan of the NC bucket counts -> coffs[NC+1] + cursor copy.
// ---------------------------------------------------------------------------
__global__ __launch_bounds__(1024) void cscan_kernel(
    const int* __restrict__ gcnt, int* __restrict__ coffs, int* __restrict__ gcur) {
    __shared__ int s[1024];
    const int t = threadIdx.x;
    int v = (t < NC) ? gcnt[t] : 0;
    s[t] = v;
    __syncthreads();
    for (int off = 1; off < 1024; off <<= 1) {
        int u = (t >= off) ? s[t - off] : 0;
        __syncthreads();
        s[t] += u;
        __syncthreads();
    }
    int excl = s[t] - v;
    if (t < NC) { coffs[t] = excl; gcur[t] = excl; }
    if (t == NC - 1) coffs[NC] = excl + v;   // == 2*N_EDGES
}

// ---------------------------------------------------------------------------
// K3: bin — write packed (local_node<<20 | edge) ints into per-bucket
// regions. Two-phase LDS ranking -> dense frontier writes (4 B each).
// ---------------------------------------------------------------------------
#define F1_EPT 16
#define F1_BLK_EDGES (256 * F1_EPT)   // 4096
__global__ __launch_bounds__(256) void bin_kernel(
    const int* __restrict__ senders, const int* __restrict__ receivers,
    int* __restrict__ gcur, int* __restrict__ pair_buf) {
    __shared__ int lcnt[NC];
    __shared__ int lbase[NC];
    for (int i = threadIdx.x; i < NC; i += 256) lcnt[i] = 0;
    __syncthreads();
    const int base_e = blockIdx.x * F1_BLK_EDGES;
    int rr[F1_EPT], ss[F1_EPT], rkr[F1_EPT], rks[F1_EPT];
#pragma unroll
    for (int j = 0; j < F1_EPT; j++) {
        int e = base_e + j * 256 + threadIdx.x;
        if (e < N_EDGES) {
            int r = receivers[e], sd = senders[e];
            rr[j] = r; ss[j] = sd;
            rkr[j] = atomicAdd(&lcnt[r / BS], 1);
            rks[j] = atomicAdd(&lcnt[NBK + sd / BS], 1);
        } else {
            rr[j] = -1;
        }
    }
    __syncthreads();
    for (int i = threadIdx.x; i < NC; i += 256) {
        int c = lcnt[i];
        lbase[i] = c ? atomicAdd(&gcur[i], c) : 0;
    }
    __syncthreads();
#pragma unroll
    for (int j = 0; j < F1_EPT; j++) {
        if (rr[j] >= 0) {
            int e = base_e + j * 256 + threadIdx.x;
            pair_buf[lbase[rr[j] / BS] + rkr[j]] = ((rr[j] & (BS - 1)) << 20) | e;
            pair_buf[lbase[NBK + ss[j] / BS] + rks[j]] = ((ss[j] & (BS - 1)) << 20) | e;
        }
    }
}

// ---------------------------------------------------------------------------
// K4: reorder — one block per bucket-side. Sort the bucket's packed entries
// by node into a fine CSR edge-id array (dense-span writes only).
// ---------------------------------------------------------------------------
__global__ __launch_bounds__(256) void reorder_kernel(
    const int* __restrict__ pair_buf, const int* __restrict__ coffs,
    int* __restrict__ eidx, int* __restrict__ offs_in, int* __restrict__ offs_out) {
    __shared__ int cur[BS];
    __shared__ int ss[256];
    const int i = blockIdx.x;
    const int side = (i >= NBK) ? 1 : 0;
    const int node_base = (side ? i - NBK : i) * BS;
    const int t = threadIdx.x;
    if (t < BS) cur[t] = 0;
    __syncthreads();
    const int p0 = coffs[i], p1 = coffs[i + 1];
    for (int p = p0 + t; p < p1; p += 256)
        atomicAdd(&cur[pair_buf[p] >> 20], 1);
    __syncthreads();
    int v = (t < BS) ? cur[t] : 0;
    ss[t] = v;
    __syncthreads();
    for (int off = 1; off < 256; off <<= 1) {
        int u = (t >= off) ? ss[t - off] : 0;
        __syncthreads();
        ss[t] += u;
        __syncthreads();
    }
    int ex = ss[t] - v;   // exclusive prefix within bucket
    int* offs = side ? offs_out : offs_in;
    if (t < BS) {
        cur[t] = ex;
        int node = node_base + t;
        if (node < N_NODES) offs[node] = p0 + ex;
    }
    if (t == 0 && node_base + BS >= N_NODES) offs[N_NODES] = p1;  // sentinel (last bucket)
    __syncthreads();
    for (int p = p0 + t; p < p1; p += 256) {
        int q = pair_buf[p];
        int rk = atomicAdd(&cur[q >> 20], 1);
        eidx[p0 + rk] = q & 0xFFFFF;
    }
}

// ---------------------------------------------------------------------------
// K5: gather — one wave per (node, side). Lane loads float4 (16 B): the
// wave covers 4 rows per load instr (16 lanes/row). ALL loads predicated
// (clamp index, mask contribution) -> no serial tail, every iteration
// issues 4 independent loads; a typical (deg~16) wave = 1 memory round.
// ---------------------------------------------------------------------------
__global__ __launch_bounds__(256) void gather_kernel(
    const float* __restrict__ edge_feat,
    const int* __restrict__ offs_in, const int* __restrict__ offs_out,
    const int* __restrict__ eidx,
    ushort* __restrict__ x) {          // [N_NODES][128] bf16
    int task = blockIdx.x * 4 + (threadIdx.x >> 6);
    if (task >= 2 * N_NODES) return;
    const int lane = threadIdx.x & 63;
    const int sub = lane >> 4;          // row-group 0..3
    const int c4 = (lane & 15) * 4;     // column base (16 lanes span a 64-col row)
    const int node = task >> 1;
    const int side = task & 1;
    const int* offs = side ? offs_out : offs_in;
    const int b = offs[node], e = offs[node + 1];
    const int last = e - 1;
    f32x4 acc = {0.f, 0.f, 0.f, 0.f};
    for (int i = b + sub; i < e; i += 16) {
        const int p1 = i + 4, p2 = i + 8, p3 = i + 12;
        int q0 = eidx[i];
        int q1 = eidx[p1 <= last ? p1 : last];
        int q2 = eidx[p2 <= last ? p2 : last];
        int q3 = eidx[p3 <= last ? p3 : last];
        f32x4 v0 = *(const f32x4*)(edge_feat + (size_t)q0 * D_EDGE + c4);
        f32x4 v1 = *(const f32x4*)(edge_feat + (size_t)q1 * D_EDGE + c4);
        f32x4 v2 = *(const f32x4*)(edge_feat + (size_t)q2 * D_EDGE + c4);
        f32x4 v3 = *(const f32x4*)(edge_feat + (size_t)q3 * D_EDGE + c4);
        const float m1 = p1 <= last ? 1.f : 0.f;
        const float m2 = p2 <= last ? 1.f : 0.f;
        const float m3 = p3 <= last ? 1.f : 0.f;
        acc += v0;
        acc += v1 * m1;
        acc += v2 * m2;
        acc += v3 * m3;
    }
    // reduce across the 4 row-groups (lanes ^16, ^32)
#pragma unroll
    for (int j = 0; j < 4; j++) {
        acc[j] += __shfl_xor(acc[j], 16, 64);
        acc[j] += __shfl_xor(acc[j], 32, 64);
    }
    if (sub == 0) {
        ushort4 o;
        o.x = f2bf(acc[0]); o.y = f2bf(acc[1]);
        o.z = f2bf(acc[2]); o.w = f2bf(acc[3]);
        *(ushort4*)(x + (size_t)node * 128 + side * 64 + c4) = o;
    }
}

// ---------------------------------------------------------------------------
// K6: pack W1/W2 (f32) into bf16 fragment-major layout for MFMA B-operands.
// ---------------------------------------------------------------------------
__global__ __launch_bounds__(256) void pack_w_kernel(
    const float* __restrict__ W1, const float* __restrict__ W2,
    ushort* __restrict__ w1p, ushort* __restrict__ w2p) {
    int idx = blockIdx.x * 256 + threadIdx.x;   // 8192 total
    if (idx < 6144) {
        int nt = idx / 384, rem = idx % 384;
        int s = rem / 64, l = rem % 64;
        int g = l >> 4, c = l & 15;
        ushort* dst = w1p + (size_t)idx * 8;
#pragma unroll
        for (int j = 0; j < 8; j++) {
            int k = s * 32 + g * 8 + j;
            dst[j] = f2bf(W1[(size_t)k * D_HID + nt * 16 + c]);
        }
    } else if (idx < 8192) {
        int id2 = idx - 6144;
        int nt = id2 / 512, rem = id2 % 512;
        int s = rem / 64, l = rem % 64;
        int g = l >> 4, c = l & 15;
        ushort* dst = w2p + (size_t)id2 * 8;
#pragma unroll
        for (int j = 0; j < 8; j++) {
            int k = s * 32 + g * 8 + j;
            dst[j] = f2bf(W2[(size_t)k * D_OUT + nt * 16 + c]);
        }
    }
}

// ---------------------------------------------------------------------------
// K7: MFMA MLP. Block = 256 thr (4 waves), 32 nodes (2 mtiles).
// ---------------------------------------------------------------------------
__global__ __launch_bounds__(256) void mlp_mfma_kernel(
    const ushort* __restrict__ x,        // [N][128] bf16
    const float* __restrict__ node_feat, // [N][64]
    const ushort* __restrict__ w1p, const float* __restrict__ b1,
    const ushort* __restrict__ w2p, const float* __restrict__ b2,
    float* __restrict__ out) {
    __shared__ ushort h_lds[32][D_HID + 8];
    const int tid = threadIdx.x;
    const int wave = tid >> 6, lane = tid & 63;
    const int g = lane >> 4, c = lane & 15;
    const int node0 = blockIdx.x * 32;

    f32x4 acc[2][4];
#pragma unroll
    for (int m = 0; m < 2; m++)
#pragma unroll
        for (int q = 0; q < 4; q++) acc[m][q] = (f32x4){0.f, 0.f, 0.f, 0.f};

    const bf16x8* w1v = (const bf16x8*)w1p;
    const bf16x8* w2v = (const bf16x8*)w2p;

    int row0 = node0 + c;      if (row0 > N_NODES - 1) row0 = N_NODES - 1;
    int row1 = node0 + 16 + c; if (row1 > N_NODES - 1) row1 = N_NODES - 1;

#pragma unroll
    for (int s = 0; s < 6; s++) {
        bf16x8 a0, a1;
        if (s < 4) {
            a0 = *(const bf16x8*)(x + (size_t)row0 * 128 + s * 32 + g * 8);
            a1 = *(const bf16x8*)(x + (size_t)row1 * 128 + s * 32 + g * 8);
        } else {
            const float* p0 = node_feat + (size_t)row0 * D_NODE + (s - 4) * 32 + g * 8;
            const float* p1 = node_feat + (size_t)row1 * D_NODE + (s - 4) * 32 + g * 8;
            union { bf16x8 v; ushort u[8]; } t0, t1;
#pragma unroll
            for (int j = 0; j < 8; j++) { t0.u[j] = f2bf(p0[j]); t1.u[j] = f2bf(p1[j]); }
            a0 = t0.v; a1 = t1.v;
        }
#pragma unroll
        for (int q = 0; q < 4; q++) {
            int nt = wave + q * 4;
            bf16x8 b = w1v[(nt * 6 + s) * 64 + lane];
            acc[0][q] = __builtin_amdgcn_mfma_f32_16x16x32_bf16(a0, b, acc[0][q], 0, 0, 0);
            acc[1][q] = __builtin_amdgcn_mfma_f32_16x16x32_bf16(a1, b, acc[1][q], 0, 0, 0);
        }
    }

#pragma unroll
    for (int q = 0; q < 4; q++) {
        int nt = wave + q * 4;
        float bv = b1[nt * 16 + c];
#pragma unroll
        for (int mt = 0; mt < 2; mt++)
#pragma unroll
            for (int r = 0; r < 4; r++) {
                int row = mt * 16 + g * 4 + r;
                h_lds[row][nt * 16 + c] = f2bf(fmaxf(acc[mt][q][r] + bv, 0.f));
            }
    }
    __syncthreads();

    f32x4 acc2[2];
    acc2[0] = (f32x4){0.f, 0.f, 0.f, 0.f};
    acc2[1] = (f32x4){0.f, 0.f, 0.f, 0.f};
#pragma unroll
    for (int s = 0; s < 8; s++) {
        bf16x8 b = w2v[(wave * 8 + s) * 64 + lane];
#pragma unroll
        for (int mt = 0; mt < 2; mt++) {
            bf16x8 a = *(const bf16x8*)(&h_lds[mt * 16 + c][s * 32 + g * 8]);
            acc2[mt] = __builtin_amdgcn_mfma_f32_16x16x32_bf16(a, b, acc2[mt], 0, 0, 0);
        }
    }
    float b2v = b2[wave * 16 + c];
#pragma unroll
    for (int mt = 0; mt < 2; mt++)
#pragma unroll
        for (int r = 0; r < 4; r++) {
            int row = node0 + mt * 16 + g * 4 + r;
            if (row < N_NODES) out[(size_t)row * D_OUT + wave * 16 + c] = acc2[mt][r] + b2v;
        }
}

extern "C" void kernel_launch(void* const* d_in, const int* in_sizes, int n_in,
                              void* d_out, int out_size, void* d_ws, size_t ws_size,
                              hipStream_t stream) {
    const float* node_feat = (const float*)d_in[0];
    const float* edge_feat = (const float*)d_in[1];
    const int* senders     = (const int*)d_in[2];
    const int* receivers   = (const int*)d_in[3];
    const float* W1        = (const float*)d_in[4];
    const float* b1        = (const float*)d_in[5];
    const float* W2        = (const float*)d_in[6];
    const float* b2        = (const float*)d_in[7];
    float* out = (float*)d_out;

    // workspace layout
    ushort* x   = (ushort*)d_ws;                         // 50000*128 bf16 = 12.8 MB
    ushort* w1p = x + (size_t)N_NODES * 128;             // 49152 bf16
    ushort* w2p = w1p + 16 * 6 * 64 * 8;                 // 16384 bf16
    int* pair_buf = (int*)(w2p + 4 * 8 * 64 * 8);        // 1.6M ints = 6.4 MB
    int* eidx     = pair_buf + (size_t)2 * N_EDGES;      // 1.6M ints = 6.4 MB
    int* offs_in  = eidx + 2 * N_EDGES;                  // N+1
    int* offs_out = offs_in + (N_NODES + 1);             // N+1
    int* gcnt     = offs_out + (N_NODES + 1);            // NC
    int* coffs    = gcnt + NC;                           // NC+1
    int* gcur     = coffs + (NC + 1);                    // NC

    hipMemsetAsync(gcnt, 0, NC * sizeof(int), stream);

    chist_kernel<<<dim3(256), dim3(256), 0, stream>>>(senders, receivers, gcnt);
    cscan_kernel<<<dim3(1), dim3(1024), 0, stream>>>(gcnt, coffs, gcur);
    {
        dim3 grid((N_EDGES + F1_BLK_EDGES - 1) / F1_BLK_EDGES);   // 196
        bin_kernel<<<grid, dim3(256), 0, stream>>>(senders, receivers, gcur, pair_buf);
    }
    reorder_kernel<<<dim3(NC), dim3(256), 0, stream>>>(pair_buf, coffs, eidx,
                                                       offs_in, offs_out);
    pack_w_kernel<<<dim3(32), dim3(256), 0, stream>>>(W1, W2, w1p, w2p);
    {
        const int tasks = 2 * N_NODES;
        dim3 grid((tasks + 3) / 4);
        gather_kernel<<<grid, dim3(256), 0, stream>>>(edge_feat, offs_in, offs_out,
                                                      eidx, x);
    }
    {
        dim3 grid((N_NODES + 31) / 32), block(256);
        mlp_mfma_kernel<<<grid, block, 0, stream>>>(x, node_feat, w1p, b1, w2p, b2, out);
    }
}